// Round 8
// baseline (778.234 us; speedup 1.0000x reference)
//
#include <hip/hip_runtime.h>
#include <hip/hip_bf16.h>

// Problem constants
constexpr int NN   = 50000;   // nodes
constexpr int NE   = 800000;  // edges
constexpr int FIN  = 128;
constexpr int HIDC = 96;
constexpr int FOUT = 64;
constexpr int NHEAD= 8;
constexpr int HCH  = 12;
constexpr int NLAY = 6;
constexpr int EVOC = 1000;
constexpr int EDIM = 32;
constexpr float ACT_SLOPE = 0.01f;
constexpr float ATT_SLOPE = 0.2f;
constexpr float GN_EPS = 1e-5f;
constexpr int GN_BLOCKS = 256;
constexpr int NSCB = (NN + 255)/256;   // scan blocks (196)

typedef _Float16 f16;
typedef __attribute__((ext_vector_type(2))) _Float16 h2;
typedef __attribute__((ext_vector_type(8))) _Float16 f16x8;
typedef __attribute__((ext_vector_type(4))) float f32x4;

__device__ __forceinline__ h2 bch2(unsigned u){ return __builtin_bit_cast(h2, u); }
__device__ __forceinline__ unsigned bcu(h2 v){ return __builtin_bit_cast(unsigned, v); }

__device__ __forceinline__ float dot2(h2 a, h2 b, float c){
#if __has_builtin(__builtin_amdgcn_fdot2)
    return __builtin_amdgcn_fdot2(a, b, c, false);
#else
    return c + (float)a.x*(float)b.x + (float)a.y*(float)b.y;
#endif
}

template<typename OT>
__device__ __forceinline__ OT cvt_out(float v){
    if constexpr (sizeof(OT)==2) return (OT)v;
    else return v;
}

// ---------------- CSR build ----------------
__global__ void k_hist(const int* __restrict__ dst, int* __restrict__ deg){
    int e = blockIdx.x*blockDim.x + threadIdx.x;
    if(e < NE) atomicAdd(&deg[dst[e]], 1);
}

__global__ __launch_bounds__(256) void k_scan1(const int* __restrict__ deg,
        int* __restrict__ pre, int* __restrict__ bsum){
    __shared__ int s[256];
    int tid = threadIdx.x;
    int idx = blockIdx.x*256 + tid;
    int v = (idx < NN) ? deg[idx] : 0;
    s[tid] = v; __syncthreads();
    #pragma unroll
    for(int off=1; off<256; off<<=1){
        int t = (tid>=off) ? s[tid-off] : 0;
        __syncthreads();
        s[tid] += t;
        __syncthreads();
    }
    if(idx < NN) pre[idx] = s[tid] - v;          // exclusive
    if(tid == 255) bsum[blockIdx.x] = s[255];    // block total
}

__global__ __launch_bounds__(256) void k_scan2(const int* __restrict__ bsum,
        int* __restrict__ boffs){
    __shared__ int s[256];
    int tid = threadIdx.x;
    int v = (tid < NSCB) ? bsum[tid] : 0;
    s[tid] = v; __syncthreads();
    #pragma unroll
    for(int off=1; off<256; off<<=1){
        int t = (tid>=off) ? s[tid-off] : 0;
        __syncthreads();
        s[tid] += t;
        __syncthreads();
    }
    if(tid < NSCB) boffs[tid] = s[tid] - v;      // exclusive
}

__global__ __launch_bounds__(256) void k_scan3(const int* __restrict__ pre,
        const int* __restrict__ boffs, int* __restrict__ rowptr, int* __restrict__ cursor){
    int tid = threadIdx.x;
    int idx = blockIdx.x*256 + tid;
    if(idx < NN){
        rowptr[idx] = pre[idx] + boffs[blockIdx.x];
        cursor[idx] = 0;                         // re-zero for scatter
    }
    if(blockIdx.x == 0 && tid == 0) rowptr[NN] = NE;
}

__global__ void k_scatter(const int* __restrict__ src, const int* __restrict__ dst,
                          const int* __restrict__ code, const float* __restrict__ ew,
                          const int* __restrict__ rowptr, int* __restrict__ cursor,
                          int2* __restrict__ epk){
    int e = blockIdx.x*blockDim.x + threadIdx.x;
    if(e >= NE) return;
    int d = dst[e];
    int pos = rowptr[d] + atomicAdd(&cursor[d], 1);
    // src < 50000 < 2^16, code < 1000 < 2^16 -> pack in one u32
    epk[pos] = make_int2((int)(((unsigned)code[e] << 16) | (unsigned)src[e]),
                         __float_as_int(ew[e]));
}

// ------- transpose + f16-pack ALL weights in one launch -------
// segs: 0..5 Wl[96x96], 6..11 Wr[96x96], 12 lin_in_W[128x96], 13 lin_out_W[96x64]
__global__ __launch_bounds__(256) void k_trall(const float* __restrict__ Wl,
        const float* __restrict__ Wr, const float* __restrict__ Win, const float* __restrict__ Wout,
        f16* __restrict__ wlt, f16* __restrict__ wrt, f16* __restrict__ wint, f16* __restrict__ wot){
    int seg = blockIdx.y;
    const float* W; f16* Wt; int K, N;
    if(seg < 6)      { W = Wl  + seg*9216;     Wt = wlt + seg*9216;     K = 96;  N = 96; }
    else if(seg < 12){ W = Wr  + (seg-6)*9216; Wt = wrt + (seg-6)*9216; K = 96;  N = 96; }
    else if(seg==12) { W = Win;                Wt = wint;               K = 128; N = 96; }
    else             { W = Wout;               Wt = wot;                K = 96;  N = 64; }
    int i = blockIdx.x*256 + threadIdx.x;
    if(i >= K*N) return;
    int k = i / N, nn = i - k*N;
    Wt[(size_t)nn*K + k] = (f16)W[i];
}

// -------- small GEMM (fp32 VALU; used for eWa only) --------
template<int K, int NC, typename OT>
__global__ __launch_bounds__(256) void k_gemm(const float* __restrict__ A,
        const float* __restrict__ W, const float* __restrict__ bias,
        OT* __restrict__ C, int M, int wstride, int cstride){
    constexpr int CPT = NC/16;
    W += (size_t)blockIdx.y * wstride;
    C += (size_t)blockIdx.y * cstride;
    __shared__ float At[K][68];
    int tid = threadIdx.x;
    int m0 = blockIdx.x*64;
    for(int i=tid; i<64*K; i+=256){
        int r = i / K, k = i - r*K;
        int row = m0 + r;
        At[k][r] = (row < M) ? A[(size_t)row*K + k] : 0.f;
    }
    __syncthreads();
    int tr = tid>>4, tc = tid&15;
    const float* wr = W + tc*CPT;
    float acc[4][CPT];
    #pragma unroll
    for(int i=0;i<4;i++)
        #pragma unroll
        for(int j=0;j<CPT;j++) acc[i][j]=0.f;
    #pragma unroll 4
    for(int k=0;k<K;k++){
        float a[4], w[CPT];
        #pragma unroll
        for(int i=0;i<4;i++) a[i] = At[k][tr*4+i];
        #pragma unroll
        for(int j=0;j<CPT;j++) w[j] = wr[k*NC + j];
        #pragma unroll
        for(int i=0;i<4;i++)
            #pragma unroll
            for(int j=0;j<CPT;j++) acc[i][j] += a[i]*w[j];
    }
    #pragma unroll
    for(int i=0;i<4;i++){
        int row = m0 + tr*4 + i;
        if(row < M){
            OT* cp = C + (size_t)row*NC + tc*CPT;
            #pragma unroll
            for(int j=0;j<CPT;j++){
                float v = acc[i][j] + (bias ? bias[tc*CPT+j] : 0.f);
                cp[j] = cvt_out<OT>(v);
            }
        }
    }
}

// -------- MFMA GEMM (f16): C[M,NC] = f(A[M,K]) @ W (optionally dual), f = GN+LeakyReLU --------
template<int K, int NC, bool GN, bool DUAL, typename OT>
__global__ __launch_bounds__(256) void k_mfgemm(const float* __restrict__ A,
        const f16* __restrict__ W1t, const float* __restrict__ b1,
        const f16* __restrict__ W2t, const float* __restrict__ b2,
        const float* __restrict__ gscale, const float* __restrict__ gshift, float slope,
        OT* __restrict__ C1, OT* __restrict__ C2, int M){
    constexpr int KP = K + 8;
    constexpr int F4R = K/4;
    constexpr int NF4 = 64*F4R;
    constexpr int KS = K/32;
    constexpr int NT = NC/16;
    __shared__ f16 At[64][KP];
    int tid = threadIdx.x;
    int m0 = blockIdx.x*64;
    for(int idx = tid; idx < NF4; idx += 256){
        int r = idx / F4R, c4 = idx - r*F4R;
        int row = m0 + r;
        float4 v = (row < M) ? ((const float4*)A)[(size_t)row*F4R + c4]
                             : make_float4(0.f,0.f,0.f,0.f);
        float vv[4] = {v.x, v.y, v.z, v.w};
        f16* dp = &At[r][c4*4];
        #pragma unroll
        for(int c=0;c<4;c++){
            float u = vv[c];
            if constexpr (GN){
                int k = c4*4 + c;
                u = gscale[k]*u + gshift[k];
                u = (u > 0.f) ? u : slope*u;
            }
            dp[c] = (f16)u;
        }
    }
    __syncthreads();
    int w = tid >> 6, l = tid & 63;
    int mrow = l & 15;
    int kg = (l >> 4) * 8;
    f32x4 acc1[NT], acc2[NT];
    #pragma unroll
    for(int nt=0; nt<NT; nt++){
        acc1[nt] = (f32x4){0.f,0.f,0.f,0.f};
        if constexpr (DUAL) acc2[nt] = (f32x4){0.f,0.f,0.f,0.f};
    }
    const f16* a_base = &At[w*16 + mrow][0];
    #pragma unroll
    for(int ks=0; ks<KS; ks++){
        f16x8 a = *(const f16x8*)(a_base + ks*32 + kg);
        #pragma unroll
        for(int nt=0; nt<NT; nt++){
            int n = nt*16 + mrow;
            f16x8 bfr = *(const f16x8*)(W1t + (size_t)n*K + ks*32 + kg);
            acc1[nt] = __builtin_amdgcn_mfma_f32_16x16x32_f16(a, bfr, acc1[nt], 0,0,0);
            if constexpr (DUAL){
                f16x8 bfr2 = *(const f16x8*)(W2t + (size_t)n*K + ks*32 + kg);
                acc2[nt] = __builtin_amdgcn_mfma_f32_16x16x32_f16(a, bfr2, acc2[nt], 0,0,0);
            }
        }
    }
    int rbase = m0 + w*16 + (l>>4)*4;
    #pragma unroll
    for(int nt=0; nt<NT; nt++){
        int n = nt*16 + mrow;
        float bb1 = b1[n];
        float bb2 = 0.f;
        if constexpr (DUAL) bb2 = b2[n];
        #pragma unroll
        for(int r=0;r<4;r++){
            int row = rbase + r;
            if(row < M){
                C1[(size_t)row*NC + n] = cvt_out<OT>(acc1[nt][r] + bb1);
                if constexpr (DUAL)
                    C2[(size_t)row*NC + n] = cvt_out<OT>(acc2[nt][r] + bb2);
            }
        }
    }
}

// ------- GraphNorm stats: grid reduce + fused last-block finalize -------
__global__ __launch_bounds__(384) void k_gn_reduce(const float* __restrict__ x,
        float* __restrict__ partial, int* __restrict__ counter,
        const float* __restrict__ w, const float* __restrict__ b, const float* __restrict__ ms,
        float* __restrict__ scale, float* __restrict__ shift){
    int tid = threadIdx.x;
    const float4* x4 = (const float4*)x;
    constexpr int TOT4 = NN*HIDC/4;
    const int stride = GN_BLOCKS*384;
    float s0=0,s1=0,s2=0,s3=0, q0=0,q1=0,q2=0,q3=0;
    for(int i = blockIdx.x*384 + tid; i < TOT4; i += stride){
        float4 v = x4[i];
        s0+=v.x; q0+=v.x*v.x;
        s1+=v.y; q1+=v.y*v.y;
        s2+=v.z; q2+=v.z*v.z;
        s3+=v.w; q3+=v.w*v.w;
    }
    __shared__ float ls[384][4], lq[384][4];
    ls[tid][0]=s0; ls[tid][1]=s1; ls[tid][2]=s2; ls[tid][3]=s3;
    lq[tid][0]=q0; lq[tid][1]=q1; lq[tid][2]=q2; lq[tid][3]=q3;
    __syncthreads();
    if(tid < 96){
        int g = tid >> 2, c = tid & 3;   // g < 24
        float a=0.f, bq=0.f;
        #pragma unroll
        for(int j=0;j<16;j++){
            a  += ls[g + 24*j][c];
            bq += lq[g + 24*j][c];
        }
        partial[blockIdx.x*192 + g*4 + c]      = a;
        partial[blockIdx.x*192 + 96 + g*4 + c] = bq;
    }
    // last-block-done: publish, count, finalize in the final block
    __syncthreads();
    __threadfence();                              // release partial writes (device scope)
    __shared__ int isLast;
    if(tid == 0) isLast = (atomicAdd(counter, 1) == GN_BLOCKS-1);
    __syncthreads();
    if(!isLast) return;
    __threadfence();                              // acquire: invalidate stale lines
    __shared__ float red[2][192];
    int v = tid % 192, seg = tid / 192;           // 2 segments of 192
    float s = 0.f;
    #pragma unroll 8
    for(int bk=seg; bk<GN_BLOCKS; bk+=2) s += partial[bk*192 + v];
    red[seg][v] = s;
    __syncthreads();
    if(tid < 192) red[0][tid] += red[1][tid];
    __syncthreads();
    if(tid < HIDC){
        float mean = red[0][tid] / (float)NN;
        float m2   = red[0][tid+96] / (float)NN;
        float mm   = ms[tid]*mean;
        float var  = m2 - 2.f*mm*mean + mm*mm;
        float sc   = w[tid] * rsqrtf(var + GN_EPS);
        scale[tid] = sc;
        shift[tid] = b[tid] - sc*mm;
    }
}

__global__ __launch_bounds__(384) void k_gn_apply(const float* __restrict__ x,
        const float* __restrict__ scale, const float* __restrict__ shift,
        float* __restrict__ out, float slope){
    int tid = threadIdx.x;
    int c = tid % HIDC;
    float sc = scale[c], sh = shift[c];
    const int total = NN*HIDC;
    const int stride = gridDim.x*384;
    for(int i=blockIdx.x*384+tid; i<total; i+=stride){
        float v = sc*x[i] + sh;
        out[i] = (v > 0.f) ? v : slope*v;
    }
}

// ---- fused GATv2 edge path: wave-per-node, zero LDS, packed-f16 math ----
// lane = (e_loc<<3)|hh. Per tile of 8 edges: lane computes edge e's head-hh logit
// via packed pk_add/pk_max + v_dot2_f32_f16, accumulates p*ew*xl into 6 packed h2.
__global__ __launch_bounds__(256, 8) void k_gat(const int* __restrict__ rowptr,
        const int2* __restrict__ epk,
        const f16* __restrict__ xl, const f16* __restrict__ xr,
        const f16* __restrict__ eW, const float* __restrict__ att_l,
        const float* __restrict__ gbias_l, float* __restrict__ h){
    int wid  = threadIdx.x >> 6;
    int lane = threadIdx.x & 63;
    int n = blockIdx.x*4 + wid;
    if(n >= NN) return;
    int r0 = rowptr[n], r1 = rowptr[n+1];
    int e_loc = lane >> 3, hh = lane & 7;
    // hoisted invariants for head hh (12 ch = 6 packed h2)
    h2 xrh[6], ath[6];
    {
        const uint2* x2 = (const uint2*)(xr + (size_t)n*HIDC + hh*HCH);
        #pragma unroll
        for(int q=0;q<3;q++){
            uint2 u = x2[q];
            xrh[2*q] = bch2(u.x); xrh[2*q+1] = bch2(u.y);
        }
        const float2* a2 = (const float2*)(att_l + hh*HCH);
        #pragma unroll
        for(int q=0;q<6;q++){
            float2 f = a2[q];
            ath[q] = (h2){(f16)f.x, (f16)f.y};
        }
    }
    const h2 slope2 = (h2){(f16)ATT_SLOPE, (f16)ATT_SLOPE};
    float m = -3.0e38f, z = 0.f;
    h2 acc[6];
    #pragma unroll
    for(int q=0;q<6;q++) acc[q] = (h2){(f16)0, (f16)0};
    for(int base = r0; base < r1; base += 8){
        int eidx = base + e_loc;
        bool val = eidx < r1;
        h2 xa[6];
        float lg = -3.0e38f, ew = 0.f;
        if(val){
            int2 ec = epk[eidx];
            unsigned sc_pack = (unsigned)ec.x;
            int s  = sc_pack & 0xffffu;
            int cd = sc_pack >> 16;
            ew = __int_as_float(ec.y);
            const uint2* xa2 = (const uint2*)(xl + (size_t)s*HIDC + hh*HCH);
            const uint2* eb2 = (const uint2*)(eW + (size_t)cd*HIDC + hh*HCH);
            uint2 xraw[3] = {xa2[0], xa2[1], xa2[2]};
            uint2 eraw[3] = {eb2[0], eb2[1], eb2[2]};
            float dot = 0.f;
            #pragma unroll
            for(int q=0;q<3;q++){
                h2 x0 = bch2(xraw[q].x), x1 = bch2(xraw[q].y);
                h2 e0 = bch2(eraw[q].x), e1 = bch2(eraw[q].y);
                xa[2*q] = x0; xa[2*q+1] = x1;
                h2 v0 = x0 + xrh[2*q]   + e0;
                h2 v1 = x1 + xrh[2*q+1] + e1;
                v0 = __builtin_elementwise_max(v0, v0*slope2);   // leaky (slope<1)
                v1 = __builtin_elementwise_max(v1, v1*slope2);
                dot = dot2(v0, ath[2*q],   dot);
                dot = dot2(v1, ath[2*q+1], dot);
            }
            lg = dot;
        } else {
            #pragma unroll
            for(int q=0;q<6;q++) xa[q] = (h2){(f16)0, (f16)0};
        }
        // online softmax per head (reduce over e-bits = lane bits 3..5)
        float tm = lg;
        tm = fmaxf(tm, __shfl_xor(tm, 8));
        tm = fmaxf(tm, __shfl_xor(tm, 16));
        tm = fmaxf(tm, __shfl_xor(tm, 32));
        float mn = fmaxf(m, tm);
        float sc = __expf(m - mn);    // first tile: 0
        float p  = __expf(lg - mn);   // invalid lanes: 0
        float zt = p;
        zt += __shfl_xor(zt, 8); zt += __shfl_xor(zt, 16); zt += __shfl_xor(zt, 32);
        z = z*sc + zt;
        m = mn;
        f16 pwh = (f16)(p * ew);
        f16 sch = (f16)sc;
        h2 pw2 = (h2){pwh, pwh};
        h2 sc2 = (h2){sch, sch};
        #pragma unroll
        for(int q=0;q<6;q++) acc[q] = acc[q]*sc2 + pw2*xa[q];
    }
    // cross-e reduction of packed accumulators (3 shfl rounds each)
    #pragma unroll
    for(int q=0;q<6;q++){
        h2 a = acc[q];
        a = a + bch2((unsigned)__shfl_xor((int)bcu(a), 8));
        a = a + bch2((unsigned)__shfl_xor((int)bcu(a), 16));
        a = a + bch2((unsigned)__shfl_xor((int)bcu(a), 32));
        acc[q] = a;
    }
    if(e_loc == 0){
        float inv = 1.f/(z + 1e-16f);
        float4* hp4 = (float4*)(h + (size_t)n*HIDC + hh*HCH);
        const float4* gb4 = (const float4*)(gbias_l + hh*HCH);
        #pragma unroll
        for(int q3=0;q3<3;q3++){
            float4 hv = hp4[q3], gv = gb4[q3];
            h2 a0 = acc[q3*2], a1 = acc[q3*2+1];
            hv.x += (float)a0.x*inv + gv.x;
            hv.y += (float)a0.y*inv + gv.y;
            hv.z += (float)a1.x*inv + gv.z;
            hv.w += (float)a1.y*inv + gv.w;
            hp4[q3] = hv;
        }
    }
}

// ---------------- launch ----------------
extern "C" void kernel_launch(void* const* d_in, const int* in_sizes, int n_in,
                              void* d_out, int out_size, void* d_ws, size_t ws_size,
                              hipStream_t stream) {
    (void)in_sizes; (void)n_in; (void)out_size; (void)ws_size;
    const float* x          = (const float*)d_in[0];
    const int*   edge_index = (const int*)  d_in[1];
    const float* edge_weight= (const float*)d_in[2];
    const int*   edge_code  = (const int*)  d_in[3];
    const float* edge_emb   = (const float*)d_in[4];
    const float* lin_in_W   = (const float*)d_in[5];
    const float* lin_in_b   = (const float*)d_in[6];
    const float* gn0_w      = (const float*)d_in[7];
    const float* gn0_b      = (const float*)d_in[8];
    const float* gn0_ms     = (const float*)d_in[9];
    const float* Wl         = (const float*)d_in[10];
    const float* bl         = (const float*)d_in[11];
    const float* Wr         = (const float*)d_in[12];
    const float* br         = (const float*)d_in[13];
    const float* We         = (const float*)d_in[14];
    const float* att        = (const float*)d_in[15];
    const float* gbias      = (const float*)d_in[16];
    const float* gn_w       = (const float*)d_in[17];
    const float* gn_b       = (const float*)d_in[18];
    const float* gn_ms      = (const float*)d_in[19];
    const float* lin_out_W  = (const float*)d_in[20];
    const float* lin_out_b  = (const float*)d_in[21];
    float* out = (float*)d_out;

    char* ws = (char*)d_ws;
    size_t off = 0;
    auto alloc = [&](size_t bytes)->void*{ void* p = ws + off; off += (bytes + 255) & ~(size_t)255; return p; };
    float* h     = (float*)alloc((size_t)NN*HIDC*4);
    f16*   xl    = (f16*)  alloc((size_t)NN*HIDC*2);
    f16*   xr    = (f16*)  alloc((size_t)NN*HIDC*2);
    f16*   eWa   = (f16*)  alloc((size_t)NLAY*EVOC*HIDC*2);
    f16*   wlt   = (f16*)  alloc((size_t)NLAY*HIDC*HIDC*2);
    f16*   wrt   = (f16*)  alloc((size_t)NLAY*HIDC*HIDC*2);
    f16*   wint  = (f16*)  alloc((size_t)FIN*HIDC*2);
    f16*   wot   = (f16*)  alloc((size_t)HIDC*FOUT*2);
    float* partial=(float*)alloc((size_t)GN_BLOCKS*2*HIDC*4);
    float* scale = (float*)alloc(HIDC*4);
    float* shift = (float*)alloc(HIDC*4);
    int* gncnt   = (int*)alloc(8*4);
    int* rowptr  = (int*)alloc((size_t)(NN+1)*4);
    int* cursor  = (int*)alloc((size_t)NN*4);
    int* pre     = (int*)alloc((size_t)NN*4);
    int* bsum    = (int*)alloc((size_t)NSCB*4);
    int* boffs   = (int*)alloc((size_t)NSCB*4);
    int2* epk    = (int2*)alloc((size_t)NE*8);

    const int* src = edge_index;
    const int* dst = edge_index + NE;

    // zero CSR histogram + per-layer GN counters
    hipMemsetAsync(cursor, 0, (size_t)NN*4, stream);
    hipMemsetAsync(gncnt, 0, 8*4, stream);

    // CSR build (dst constant across layers -> built once per call)
    k_hist<<<(NE+255)/256, 256, 0, stream>>>(dst, cursor);
    k_scan1<<<NSCB, 256, 0, stream>>>(cursor, pre, bsum);
    k_scan2<<<1, 256, 0, stream>>>(bsum, boffs);
    k_scan3<<<NSCB, 256, 0, stream>>>(pre, boffs, rowptr, cursor);
    k_scatter<<<(NE+255)/256, 256, 0, stream>>>(src, dst, edge_code, edge_weight,
                                                rowptr, cursor, epk);

    // all weight transposes (f16) in one launch
    k_trall<<<dim3(48, 14), 256, 0, stream>>>(Wl, Wr, lin_in_W, lin_out_W,
                                              wlt, wrt, wint, wot);

    // edge-vocab transform, all 6 layers: eWa[l] = edge_emb @ We[l] (f16 out)
    k_gemm<EDIM,HIDC,f16><<<dim3((EVOC+63)/64, NLAY), 256, 0, stream>>>(
        edge_emb, We, nullptr, eWa, EVOC, EDIM*HIDC, EVOC*HIDC);

    // lin_in -> h (fp32 out, f16 MFMA inputs)
    k_mfgemm<FIN,HIDC,false,false,float><<<(NN+63)/64, 256, 0, stream>>>(
        x, wint, lin_in_b, nullptr, nullptr, nullptr, nullptr, 0.f, h, nullptr, NN);

    // gn0 (no activation), in-place on h
    k_gn_reduce<<<GN_BLOCKS, 384, 0, stream>>>(h, partial, gncnt+0,
                                               gn0_w, gn0_b, gn0_ms, scale, shift);
    k_gn_apply<<<768, 384, 0, stream>>>(h, scale, shift, h, 1.0f);

    for(int l=0;l<NLAY;l++){
        k_gn_reduce<<<GN_BLOCKS, 384, 0, stream>>>(h, partial, gncnt+1+l,
                                                   gn_w + l*HIDC, gn_b + l*HIDC, gn_ms + l*HIDC,
                                                   scale, shift);
        // fused dual MFMA GEMM: GN+LeakyReLU in A-stage, xl & xr in one pass
        k_mfgemm<HIDC,HIDC,true,true,f16><<<(NN+63)/64, 256, 0, stream>>>(
            h, wlt + (size_t)l*HIDC*HIDC, bl + l*HIDC,
               wrt + (size_t)l*HIDC*HIDC, br + l*HIDC,
            scale, shift, ACT_SLOPE, xl, xr, NN);
        // fused logits + online softmax + aggregate + residual (wave per node, no LDS)
        k_gat<<<(NN+3)/4, 256, 0, stream>>>(rowptr, epk, xl, xr,
                                            eWa + (size_t)l*EVOC*HIDC, att + l*NHEAD*HCH,
                                            gbias + l*HIDC, h);
    }

    // lin_out -> d_out (fp32 out, f16 MFMA inputs)
    k_mfgemm<HIDC,FOUT,false,false,float><<<(NN+63)/64, 256, 0, stream>>>(
        h, wot, lin_out_b, nullptr, nullptr, nullptr, nullptr, 0.f, out, nullptr, NN);
}

// Round 9
// 600.414 us; speedup vs baseline: 1.2962x; 1.2962x over previous
//
#include <hip/hip_runtime.h>
#include <hip/hip_bf16.h>

// Problem constants
constexpr int NN   = 50000;   // nodes
constexpr int NE   = 800000;  // edges
constexpr int FIN  = 128;
constexpr int HIDC = 96;
constexpr int FOUT = 64;
constexpr int NHEAD= 8;
constexpr int HCH  = 12;
constexpr int NLAY = 6;
constexpr int EVOC = 1000;
constexpr int EDIM = 32;
constexpr float ACT_SLOPE = 0.01f;
constexpr float ATT_SLOPE = 0.2f;
constexpr float GN_EPS = 1e-5f;
constexpr int GN_BLOCKS = 256;
constexpr int NSCB = (NN + 255)/256;   // scan blocks (196)

typedef _Float16 f16;
typedef __attribute__((ext_vector_type(2))) _Float16 h2;
typedef __attribute__((ext_vector_type(8))) _Float16 f16x8;
typedef __attribute__((ext_vector_type(4))) float f32x4;

__device__ __forceinline__ h2 bch2(unsigned u){ return __builtin_bit_cast(h2, u); }
__device__ __forceinline__ unsigned bcu(h2 v){ return __builtin_bit_cast(unsigned, v); }

__device__ __forceinline__ float dot2(h2 a, h2 b, float c){
#if __has_builtin(__builtin_amdgcn_fdot2)
    return __builtin_amdgcn_fdot2(a, b, c, false);
#else
    return c + (float)a.x*(float)b.x + (float)a.y*(float)b.y;
#endif
}

template<typename OT>
__device__ __forceinline__ OT cvt_out(float v){
    if constexpr (sizeof(OT)==2) return (OT)v;
    else return v;
}

// ---------------- CSR build ----------------
__global__ void k_hist(const int* __restrict__ dst, int* __restrict__ deg){
    int e = blockIdx.x*blockDim.x + threadIdx.x;
    if(e < NE) atomicAdd(&deg[dst[e]], 1);
}

__global__ __launch_bounds__(256) void k_scan1(const int* __restrict__ deg,
        int* __restrict__ pre, int* __restrict__ bsum){
    __shared__ int s[256];
    int tid = threadIdx.x;
    int idx = blockIdx.x*256 + tid;
    int v = (idx < NN) ? deg[idx] : 0;
    s[tid] = v; __syncthreads();
    #pragma unroll
    for(int off=1; off<256; off<<=1){
        int t = (tid>=off) ? s[tid-off] : 0;
        __syncthreads();
        s[tid] += t;
        __syncthreads();
    }
    if(idx < NN) pre[idx] = s[tid] - v;          // exclusive
    if(tid == 255) bsum[blockIdx.x] = s[255];    // block total
}

__global__ __launch_bounds__(256) void k_scan2(const int* __restrict__ bsum,
        int* __restrict__ boffs){
    __shared__ int s[256];
    int tid = threadIdx.x;
    int v = (tid < NSCB) ? bsum[tid] : 0;
    s[tid] = v; __syncthreads();
    #pragma unroll
    for(int off=1; off<256; off<<=1){
        int t = (tid>=off) ? s[tid-off] : 0;
        __syncthreads();
        s[tid] += t;
        __syncthreads();
    }
    if(tid < NSCB) boffs[tid] = s[tid] - v;      // exclusive
}

__global__ __launch_bounds__(256) void k_scan3(const int* __restrict__ pre,
        const int* __restrict__ boffs, int* __restrict__ rowptr, int* __restrict__ cursor){
    int tid = threadIdx.x;
    int idx = blockIdx.x*256 + tid;
    if(idx < NN){
        rowptr[idx] = pre[idx] + boffs[blockIdx.x];
        cursor[idx] = 0;                         // re-zero for scatter
    }
    if(blockIdx.x == 0 && tid == 0) rowptr[NN] = NE;
}

__global__ void k_scatter(const int* __restrict__ src, const int* __restrict__ dst,
                          const int* __restrict__ code, const float* __restrict__ ew,
                          const int* __restrict__ rowptr, int* __restrict__ cursor,
                          int2* __restrict__ epk){
    int e = blockIdx.x*blockDim.x + threadIdx.x;
    if(e >= NE) return;
    int d = dst[e];
    int pos = rowptr[d] + atomicAdd(&cursor[d], 1);
    // src < 50000 < 2^16, code < 1000 < 2^16 -> pack in one u32
    epk[pos] = make_int2((int)(((unsigned)code[e] << 16) | (unsigned)src[e]),
                         __float_as_int(ew[e]));
}

// ------- transpose + f16-pack ALL weights in one launch -------
__global__ __launch_bounds__(256) void k_trall(const float* __restrict__ Wl,
        const float* __restrict__ Wr, const float* __restrict__ Win, const float* __restrict__ Wout,
        f16* __restrict__ wlt, f16* __restrict__ wrt, f16* __restrict__ wint, f16* __restrict__ wot){
    int seg = blockIdx.y;
    const float* W; f16* Wt; int K, N;
    if(seg < 6)      { W = Wl  + seg*9216;     Wt = wlt + seg*9216;     K = 96;  N = 96; }
    else if(seg < 12){ W = Wr  + (seg-6)*9216; Wt = wrt + (seg-6)*9216; K = 96;  N = 96; }
    else if(seg==12) { W = Win;                Wt = wint;               K = 128; N = 96; }
    else             { W = Wout;               Wt = wot;                K = 96;  N = 64; }
    int i = blockIdx.x*256 + threadIdx.x;
    if(i >= K*N) return;
    int k = i / N, nn = i - k*N;
    Wt[(size_t)nn*K + k] = (f16)W[i];
}

// -------- small GEMM (fp32 VALU; used for eWa only) --------
template<int K, int NC, typename OT>
__global__ __launch_bounds__(256) void k_gemm(const float* __restrict__ A,
        const float* __restrict__ W, const float* __restrict__ bias,
        OT* __restrict__ C, int M, int wstride, int cstride){
    constexpr int CPT = NC/16;
    W += (size_t)blockIdx.y * wstride;
    C += (size_t)blockIdx.y * cstride;
    __shared__ float At[K][68];
    int tid = threadIdx.x;
    int m0 = blockIdx.x*64;
    for(int i=tid; i<64*K; i+=256){
        int r = i / K, k = i - r*K;
        int row = m0 + r;
        At[k][r] = (row < M) ? A[(size_t)row*K + k] : 0.f;
    }
    __syncthreads();
    int tr = tid>>4, tc = tid&15;
    const float* wr = W + tc*CPT;
    float acc[4][CPT];
    #pragma unroll
    for(int i=0;i<4;i++)
        #pragma unroll
        for(int j=0;j<CPT;j++) acc[i][j]=0.f;
    #pragma unroll 4
    for(int k=0;k<K;k++){
        float a[4], w[CPT];
        #pragma unroll
        for(int i=0;i<4;i++) a[i] = At[k][tr*4+i];
        #pragma unroll
        for(int j=0;j<CPT;j++) w[j] = wr[k*NC + j];
        #pragma unroll
        for(int i=0;i<4;i++)
            #pragma unroll
            for(int j=0;j<CPT;j++) acc[i][j] += a[i]*w[j];
    }
    #pragma unroll
    for(int i=0;i<4;i++){
        int row = m0 + tr*4 + i;
        if(row < M){
            OT* cp = C + (size_t)row*NC + tc*CPT;
            #pragma unroll
            for(int j=0;j<CPT;j++){
                float v = acc[i][j] + (bias ? bias[tc*CPT+j] : 0.f);
                cp[j] = cvt_out<OT>(v);
            }
        }
    }
}

// -------- MFMA GEMM (f16): C[M,NC] = f(A[M,K]) @ W (optionally dual), f = GN+LeakyReLU --------
template<int K, int NC, bool GN, bool DUAL, typename OT>
__global__ __launch_bounds__(256) void k_mfgemm(const float* __restrict__ A,
        const f16* __restrict__ W1t, const float* __restrict__ b1,
        const f16* __restrict__ W2t, const float* __restrict__ b2,
        const float* __restrict__ gscale, const float* __restrict__ gshift, float slope,
        OT* __restrict__ C1, OT* __restrict__ C2, int M){
    constexpr int KP = K + 8;
    constexpr int F4R = K/4;
    constexpr int NF4 = 64*F4R;
    constexpr int KS = K/32;
    constexpr int NT = NC/16;
    __shared__ f16 At[64][KP];
    int tid = threadIdx.x;
    int m0 = blockIdx.x*64;
    for(int idx = tid; idx < NF4; idx += 256){
        int r = idx / F4R, c4 = idx - r*F4R;
        int row = m0 + r;
        float4 v = (row < M) ? ((const float4*)A)[(size_t)row*F4R + c4]
                             : make_float4(0.f,0.f,0.f,0.f);
        float vv[4] = {v.x, v.y, v.z, v.w};
        f16* dp = &At[r][c4*4];
        #pragma unroll
        for(int c=0;c<4;c++){
            float u = vv[c];
            if constexpr (GN){
                int k = c4*4 + c;
                u = gscale[k]*u + gshift[k];
                u = (u > 0.f) ? u : slope*u;
            }
            dp[c] = (f16)u;
        }
    }
    __syncthreads();
    int w = tid >> 6, l = tid & 63;
    int mrow = l & 15;
    int kg = (l >> 4) * 8;
    f32x4 acc1[NT], acc2[NT];
    #pragma unroll
    for(int nt=0; nt<NT; nt++){
        acc1[nt] = (f32x4){0.f,0.f,0.f,0.f};
        if constexpr (DUAL) acc2[nt] = (f32x4){0.f,0.f,0.f,0.f};
    }
    const f16* a_base = &At[w*16 + mrow][0];
    #pragma unroll
    for(int ks=0; ks<KS; ks++){
        f16x8 a = *(const f16x8*)(a_base + ks*32 + kg);
        #pragma unroll
        for(int nt=0; nt<NT; nt++){
            int n = nt*16 + mrow;
            f16x8 bfr = *(const f16x8*)(W1t + (size_t)n*K + ks*32 + kg);
            acc1[nt] = __builtin_amdgcn_mfma_f32_16x16x32_f16(a, bfr, acc1[nt], 0,0,0);
            if constexpr (DUAL){
                f16x8 bfr2 = *(const f16x8*)(W2t + (size_t)n*K + ks*32 + kg);
                acc2[nt] = __builtin_amdgcn_mfma_f32_16x16x32_f16(a, bfr2, acc2[nt], 0,0,0);
            }
        }
    }
    int rbase = m0 + w*16 + (l>>4)*4;
    #pragma unroll
    for(int nt=0; nt<NT; nt++){
        int n = nt*16 + mrow;
        float bb1 = b1[n];
        float bb2 = 0.f;
        if constexpr (DUAL) bb2 = b2[n];
        #pragma unroll
        for(int r=0;r<4;r++){
            int row = rbase + r;
            if(row < M){
                C1[(size_t)row*NC + n] = cvt_out<OT>(acc1[nt][r] + bb1);
                if constexpr (DUAL)
                    C2[(size_t)row*NC + n] = cvt_out<OT>(acc2[nt][r] + bb2);
            }
        }
    }
}

// ---------------- GraphNorm stats (split kernels — no device fences) ----------------
__global__ __launch_bounds__(384) void k_gn_reduce(const float* __restrict__ x, float* __restrict__ partial){
    int tid = threadIdx.x;
    const float4* x4 = (const float4*)x;
    constexpr int TOT4 = NN*HIDC/4;
    const int stride = GN_BLOCKS*384;
    float s0=0,s1=0,s2=0,s3=0, q0=0,q1=0,q2=0,q3=0;
    for(int i = blockIdx.x*384 + tid; i < TOT4; i += stride){
        float4 v = x4[i];
        s0+=v.x; q0+=v.x*v.x;
        s1+=v.y; q1+=v.y*v.y;
        s2+=v.z; q2+=v.z*v.z;
        s3+=v.w; q3+=v.w*v.w;
    }
    __shared__ float ls[384][4], lq[384][4];
    ls[tid][0]=s0; ls[tid][1]=s1; ls[tid][2]=s2; ls[tid][3]=s3;
    lq[tid][0]=q0; lq[tid][1]=q1; lq[tid][2]=q2; lq[tid][3]=q3;
    __syncthreads();
    if(tid < 96){
        int g = tid >> 2, c = tid & 3;   // g < 24
        float a=0.f, bq=0.f;
        #pragma unroll
        for(int j=0;j<16;j++){
            a  += ls[g + 24*j][c];
            bq += lq[g + 24*j][c];
        }
        partial[blockIdx.x*192 + g*4 + c]      = a;
        partial[blockIdx.x*192 + 96 + g*4 + c] = bq;
    }
}

__global__ __launch_bounds__(768) void k_gn_finalize(const float* __restrict__ partial,
        const float* __restrict__ w, const float* __restrict__ b, const float* __restrict__ ms,
        float* __restrict__ scale, float* __restrict__ shift){
    __shared__ float red[4][192];
    int tid = threadIdx.x;
    int v = tid % 192, seg = tid / 192;
    float s = 0.f;
    #pragma unroll 8
    for(int bk=seg; bk<GN_BLOCKS; bk+=4) s += partial[bk*192 + v];
    red[seg][v] = s;
    __syncthreads();
    if(tid < 192) red[0][tid] = red[0][tid]+red[1][tid]+red[2][tid]+red[3][tid];
    __syncthreads();
    if(tid < HIDC){
        float mean = red[0][tid] / (float)NN;
        float m2   = red[0][tid+96] / (float)NN;
        float mm   = ms[tid]*mean;
        float var  = m2 - 2.f*mm*mean + mm*mm;
        float sc   = w[tid] * rsqrtf(var + GN_EPS);
        scale[tid] = sc;
        shift[tid] = b[tid] - sc*mm;
    }
}

__global__ __launch_bounds__(384) void k_gn_apply(const float* __restrict__ x,
        const float* __restrict__ scale, const float* __restrict__ shift,
        float* __restrict__ out, float slope){
    int tid = threadIdx.x;
    int c = tid % HIDC;
    float sc = scale[c], sh = shift[c];
    const int total = NN*HIDC;
    const int stride = gridDim.x*384;
    for(int i=blockIdx.x*384+tid; i<total; i+=stride){
        float v = sc*x[i] + sh;
        out[i] = (v > 0.f) ? v : slope*v;
    }
}

// ---- fused GATv2 edge path: wave-per-node, zero LDS, packed-f16, 16-edge tiles ----
// lane = (e_loc<<3)|hh handles edges base+e_loc and base+8+e_loc for head hh.
// Both half-tiles' gathers issued before compute -> 2x outstanding loads; one
// shfl-reduce pass covers all 16 edges.
__global__ __launch_bounds__(256, 6) void k_gat(const int* __restrict__ rowptr,
        const int2* __restrict__ epk,
        const f16* __restrict__ xl, const f16* __restrict__ xr,
        const f16* __restrict__ eW, const float* __restrict__ att_l,
        const float* __restrict__ gbias_l, float* __restrict__ h){
    int wid  = threadIdx.x >> 6;
    int lane = threadIdx.x & 63;
    int n = blockIdx.x*4 + wid;
    if(n >= NN) return;
    int r0 = rowptr[n], r1 = rowptr[n+1];
    int e_loc = lane >> 3, hh = lane & 7;
    // hoisted invariants for head hh (12 ch = 6 packed h2)
    h2 xrh[6], ath[6];
    {
        const uint2* x2 = (const uint2*)(xr + (size_t)n*HIDC + hh*HCH);
        #pragma unroll
        for(int q=0;q<3;q++){
            uint2 u = x2[q];
            xrh[2*q] = bch2(u.x); xrh[2*q+1] = bch2(u.y);
        }
        const float2* a2 = (const float2*)(att_l + hh*HCH);
        #pragma unroll
        for(int q=0;q<6;q++){
            float2 f = a2[q];
            ath[q] = (h2){(f16)f.x, (f16)f.y};
        }
    }
    const h2 slope2 = (h2){(f16)ATT_SLOPE, (f16)ATT_SLOPE};
    float m = -3.0e38f, z = 0.f;
    h2 acc[6];
    #pragma unroll
    for(int q=0;q<6;q++) acc[q] = (h2){(f16)0, (f16)0};
    for(int base = r0; base < r1; base += 16){
        int eiA = base + e_loc;
        int eiB = base + 8 + e_loc;
        bool vA = eiA < r1, vB = eiB < r1;
        // issue all loads for both half-tiles first
        int2 ecA = vA ? epk[eiA] : make_int2(0,0);
        int2 ecB = vB ? epk[eiB] : make_int2(0,0);
        uint2 xrawA[3] = {{0,0},{0,0},{0,0}}, erawA[3] = {{0,0},{0,0},{0,0}};
        uint2 xrawB[3] = {{0,0},{0,0},{0,0}}, erawB[3] = {{0,0},{0,0},{0,0}};
        float ewA = 0.f, ewB = 0.f;
        if(vA){
            unsigned pk = (unsigned)ecA.x;
            ewA = __int_as_float(ecA.y);
            const uint2* xa2 = (const uint2*)(xl + (size_t)(pk & 0xffffu)*HIDC + hh*HCH);
            const uint2* eb2 = (const uint2*)(eW + (size_t)(pk >> 16)*HIDC + hh*HCH);
            xrawA[0]=xa2[0]; xrawA[1]=xa2[1]; xrawA[2]=xa2[2];
            erawA[0]=eb2[0]; erawA[1]=eb2[1]; erawA[2]=eb2[2];
        }
        if(vB){
            unsigned pk = (unsigned)ecB.x;
            ewB = __int_as_float(ecB.y);
            const uint2* xa2 = (const uint2*)(xl + (size_t)(pk & 0xffffu)*HIDC + hh*HCH);
            const uint2* eb2 = (const uint2*)(eW + (size_t)(pk >> 16)*HIDC + hh*HCH);
            xrawB[0]=xa2[0]; xrawB[1]=xa2[1]; xrawB[2]=xa2[2];
            erawB[0]=eb2[0]; erawB[1]=eb2[1]; erawB[2]=eb2[2];
        }
        // logits
        h2 xaA[6], xaB[6];
        float lgA = -3.0e38f, lgB = -3.0e38f;
        {
            float dot = 0.f;
            #pragma unroll
            for(int q=0;q<3;q++){
                h2 x0 = bch2(xrawA[q].x), x1 = bch2(xrawA[q].y);
                h2 e0 = bch2(erawA[q].x), e1 = bch2(erawA[q].y);
                xaA[2*q] = x0; xaA[2*q+1] = x1;
                h2 v0 = x0 + xrh[2*q]   + e0;
                h2 v1 = x1 + xrh[2*q+1] + e1;
                v0 = __builtin_elementwise_max(v0, v0*slope2);
                v1 = __builtin_elementwise_max(v1, v1*slope2);
                dot = dot2(v0, ath[2*q],   dot);
                dot = dot2(v1, ath[2*q+1], dot);
            }
            if(vA) lgA = dot;
        }
        {
            float dot = 0.f;
            #pragma unroll
            for(int q=0;q<3;q++){
                h2 x0 = bch2(xrawB[q].x), x1 = bch2(xrawB[q].y);
                h2 e0 = bch2(erawB[q].x), e1 = bch2(erawB[q].y);
                xaB[2*q] = x0; xaB[2*q+1] = x1;
                h2 v0 = x0 + xrh[2*q]   + e0;
                h2 v1 = x1 + xrh[2*q+1] + e1;
                v0 = __builtin_elementwise_max(v0, v0*slope2);
                v1 = __builtin_elementwise_max(v1, v1*slope2);
                dot = dot2(v0, ath[2*q],   dot);
                dot = dot2(v1, ath[2*q+1], dot);
            }
            if(vB) lgB = dot;
        }
        // online softmax over 16 edges in one reduce pass
        float tm = fmaxf(lgA, lgB);
        tm = fmaxf(tm, __shfl_xor(tm, 8));
        tm = fmaxf(tm, __shfl_xor(tm, 16));
        tm = fmaxf(tm, __shfl_xor(tm, 32));
        float mn = fmaxf(m, tm);
        float sc = __expf(m - mn);     // first tile: 0
        float pA = __expf(lgA - mn);   // invalid: 0
        float pB = __expf(lgB - mn);
        float zt = pA + pB;
        zt += __shfl_xor(zt, 8); zt += __shfl_xor(zt, 16); zt += __shfl_xor(zt, 32);
        z = z*sc + zt;
        m = mn;
        f16 pwA = (f16)(pA * ewA);
        f16 pwB = (f16)(pB * ewB);
        f16 sch = (f16)sc;
        h2 pwA2 = (h2){pwA, pwA};
        h2 pwB2 = (h2){pwB, pwB};
        h2 sc2  = (h2){sch, sch};
        #pragma unroll
        for(int q=0;q<6;q++) acc[q] = (acc[q]*sc2 + pwA2*xaA[q]) + pwB2*xaB[q];
    }
    // cross-e reduction of packed accumulators (3 shfl rounds each)
    #pragma unroll
    for(int q=0;q<6;q++){
        h2 a = acc[q];
        a = a + bch2((unsigned)__shfl_xor((int)bcu(a), 8));
        a = a + bch2((unsigned)__shfl_xor((int)bcu(a), 16));
        a = a + bch2((unsigned)__shfl_xor((int)bcu(a), 32));
        acc[q] = a;
    }
    if(e_loc == 0){
        float inv = 1.f/(z + 1e-16f);
        float4* hp4 = (float4*)(h + (size_t)n*HIDC + hh*HCH);
        const float4* gb4 = (const float4*)(gbias_l + hh*HCH);
        #pragma unroll
        for(int q3=0;q3<3;q3++){
            float4 hv = hp4[q3], gv = gb4[q3];
            h2 a0 = acc[q3*2], a1 = acc[q3*2+1];
            hv.x += (float)a0.x*inv + gv.x;
            hv.y += (float)a0.y*inv + gv.y;
            hv.z += (float)a1.x*inv + gv.z;
            hv.w += (float)a1.y*inv + gv.w;
            hp4[q3] = hv;
        }
    }
}

// ---------------- launch ----------------
extern "C" void kernel_launch(void* const* d_in, const int* in_sizes, int n_in,
                              void* d_out, int out_size, void* d_ws, size_t ws_size,
                              hipStream_t stream) {
    (void)in_sizes; (void)n_in; (void)out_size; (void)ws_size;
    const float* x          = (const float*)d_in[0];
    const int*   edge_index = (const int*)  d_in[1];
    const float* edge_weight= (const float*)d_in[2];
    const int*   edge_code  = (const int*)  d_in[3];
    const float* edge_emb   = (const float*)d_in[4];
    const float* lin_in_W   = (const float*)d_in[5];
    const float* lin_in_b   = (const float*)d_in[6];
    const float* gn0_w      = (const float*)d_in[7];
    const float* gn0_b      = (const float*)d_in[8];
    const float* gn0_ms     = (const float*)d_in[9];
    const float* Wl         = (const float*)d_in[10];
    const float* bl         = (const float*)d_in[11];
    const float* Wr         = (const float*)d_in[12];
    const float* br         = (const float*)d_in[13];
    const float* We         = (const float*)d_in[14];
    const float* att        = (const float*)d_in[15];
    const float* gbias      = (const float*)d_in[16];
    const float* gn_w       = (const float*)d_in[17];
    const float* gn_b       = (const float*)d_in[18];
    const float* gn_ms      = (const float*)d_in[19];
    const float* lin_out_W  = (const float*)d_in[20];
    const float* lin_out_b  = (const float*)d_in[21];
    float* out = (float*)d_out;

    char* ws = (char*)d_ws;
    size_t off = 0;
    auto alloc = [&](size_t bytes)->void*{ void* p = ws + off; off += (bytes + 255) & ~(size_t)255; return p; };
    float* h     = (float*)alloc((size_t)NN*HIDC*4);
    f16*   xl    = (f16*)  alloc((size_t)NN*HIDC*2);
    f16*   xr    = (f16*)  alloc((size_t)NN*HIDC*2);
    f16*   eWa   = (f16*)  alloc((size_t)NLAY*EVOC*HIDC*2);
    f16*   wlt   = (f16*)  alloc((size_t)NLAY*HIDC*HIDC*2);
    f16*   wrt   = (f16*)  alloc((size_t)NLAY*HIDC*HIDC*2);
    f16*   wint  = (f16*)  alloc((size_t)FIN*HIDC*2);
    f16*   wot   = (f16*)  alloc((size_t)HIDC*FOUT*2);
    float* partial=(float*)alloc((size_t)GN_BLOCKS*2*HIDC*4);
    float* scale = (float*)alloc(HIDC*4);
    float* shift = (float*)alloc(HIDC*4);
    int* rowptr  = (int*)alloc((size_t)(NN+1)*4);
    int* cursor  = (int*)alloc((size_t)NN*4);
    int* pre     = (int*)alloc((size_t)NN*4);
    int* bsum    = (int*)alloc((size_t)NSCB*4);
    int* boffs   = (int*)alloc((size_t)NSCB*4);
    int2* epk    = (int2*)alloc((size_t)NE*8);

    const int* src = edge_index;
    const int* dst = edge_index + NE;

    // CSR build (dst constant across layers -> built once per call)
    hipMemsetAsync(cursor, 0, (size_t)NN*4, stream);
    k_hist<<<(NE+255)/256, 256, 0, stream>>>(dst, cursor);
    k_scan1<<<NSCB, 256, 0, stream>>>(cursor, pre, bsum);
    k_scan2<<<1, 256, 0, stream>>>(bsum, boffs);
    k_scan3<<<NSCB, 256, 0, stream>>>(pre, boffs, rowptr, cursor);
    k_scatter<<<(NE+255)/256, 256, 0, stream>>>(src, dst, edge_code, edge_weight,
                                                rowptr, cursor, epk);

    // all weight transposes (f16) in one launch
    k_trall<<<dim3(48, 14), 256, 0, stream>>>(Wl, Wr, lin_in_W, lin_out_W,
                                              wlt, wrt, wint, wot);

    // edge-vocab transform, all 6 layers: eWa[l] = edge_emb @ We[l] (f16 out)
    k_gemm<EDIM,HIDC,f16><<<dim3((EVOC+63)/64, NLAY), 256, 0, stream>>>(
        edge_emb, We, nullptr, eWa, EVOC, EDIM*HIDC, EVOC*HIDC);

    // lin_in -> h (fp32 out, f16 MFMA inputs)
    k_mfgemm<FIN,HIDC,false,false,float><<<(NN+63)/64, 256, 0, stream>>>(
        x, wint, lin_in_b, nullptr, nullptr, nullptr, nullptr, 0.f, h, nullptr, NN);

    // gn0 (no activation), in-place on h
    k_gn_reduce<<<GN_BLOCKS, 384, 0, stream>>>(h, partial);
    k_gn_finalize<<<1, 768, 0, stream>>>(partial, gn0_w, gn0_b, gn0_ms, scale, shift);
    k_gn_apply<<<768, 384, 0, stream>>>(h, scale, shift, h, 1.0f);

    for(int l=0;l<NLAY;l++){
        k_gn_reduce<<<GN_BLOCKS, 384, 0, stream>>>(h, partial);
        k_gn_finalize<<<1, 768, 0, stream>>>(partial, gn_w + l*HIDC, gn_b + l*HIDC,
                                             gn_ms + l*HIDC, scale, shift);
        // fused dual MFMA GEMM: GN+LeakyReLU in A-stage, xl & xr in one pass
        k_mfgemm<HIDC,HIDC,true,true,f16><<<(NN+63)/64, 256, 0, stream>>>(
            h, wlt + (size_t)l*HIDC*HIDC, bl + l*HIDC,
               wrt + (size_t)l*HIDC*HIDC, br + l*HIDC,
            scale, shift, ACT_SLOPE, xl, xr, NN);
        // fused logits + online softmax + aggregate + residual (wave per node, no LDS)
        k_gat<<<(NN+3)/4, 256, 0, stream>>>(rowptr, epk, xl, xr,
                                            eWa + (size_t)l*EVOC*HIDC, att + l*NHEAD*HCH,
                                            gbias + l*HIDC, h);
    }

    // lin_out -> d_out (fp32 out, f16 MFMA inputs)
    k_mfgemm<HIDC,FOUT,false,false,float><<<(NN+63)/64, 256, 0, stream>>>(
        h, wot, lin_out_b, nullptr, nullptr, nullptr, nullptr, 0.f, out, nullptr, NN);
}